// Round 5
// baseline (40.712 us; speedup 1.0000x reference)
//
#include <hip/hip_runtime.h>

#define DIM 10
#define BATCH 65536

typedef float v2f __attribute__((ext_vector_type(2)));

static __device__ __forceinline__ v2f vfma2(v2f a, v2f b, v2f c) {
    return __builtin_elementwise_fma(a, b, c);
}
static __device__ __forceinline__ v2f vmax2(v2f a, v2f b) {
    return __builtin_elementwise_max(a, b);
}

// MEASUREMENT ROUND: R2 structure, conv phase repeated 4x (numerically
// identical; opaque zero defeats CSE, multiplicative acc chain defeats DCE)
// so this dispatch outlasts the 40us poison fills and shows up in rocprof
// top-5 with real counters. dur_probe = staging + 4*compute.
__launch_bounds__(256, 1)
__global__ void net_kernel(const float* __restrict__ x,
                           const float* __restrict__ w1,
                           const float* __restrict__ b1,
                           const float* __restrict__ w2,
                           const float* __restrict__ b2,
                           const float* __restrict__ fc1_w,
                           const float* __restrict__ fc1_b,
                           const float* __restrict__ fc2_w,
                           const float* __restrict__ fc2_b,
                           float* __restrict__ out) {
    __shared__ __align__(16) float xs[256 * DIM * DIM];

    const int tid  = threadIdx.x;
    const int wave = tid >> 6;
    const int lane = tid & 63;
    const size_t blk_elem0 = (size_t)blockIdx.x * 256;

    // ---- Phase 1: coalesced global -> LDS staging ----
    const float* gbase = x + blk_elem0 * (DIM * DIM);
    #pragma unroll
    for (int i = 0; i < 25; ++i) {
        const int chunk = wave * 25 + i;
        __builtin_amdgcn_global_load_lds(
            (const __attribute__((address_space(1))) void*)(gbase + chunk * 256 + lane * 4),
            (__attribute__((address_space(3))) void*)(xs + chunk * 256),
            16, 0, 0);
    }

    // ---- weights to registers while loads fly ----
    v2f W1p[5], B1p[5];
    #pragma unroll
    for (int cp = 0; cp < 5; ++cp) {
        W1p[cp] = (v2f){w1[2 * cp], w1[2 * cp + 1]};
        B1p[cp] = (v2f){b1[2 * cp], b1[2 * cp + 1]};
    }
    v2f W2p[5][9];
    #pragma unroll
    for (int cp = 0; cp < 5; ++cp)
        #pragma unroll
        for (int k = 0; k < 9; ++k)
            W2p[cp][k] = (v2f){w2[(2 * cp) * 9 + k], w2[(2 * cp + 1) * 9 + k]};
    const float B2 = b2[0];

    __syncthreads();

    // ---- Phase 2: per-thread row/col sums from LDS ----
    float row[DIM], col[DIM];
    #pragma unroll
    for (int i = 0; i < DIM; ++i) { row[i] = 0.f; col[i] = 0.f; }
    const float4* xb = reinterpret_cast<const float4*>(xs + tid * (DIM * DIM));
    #pragma unroll
    for (int t = 0; t < 25; ++t) {
        const float4 v = xb[t];
        const int e0 = t * 4;
        row[(e0 + 0) / DIM] += v.x; col[(e0 + 0) % DIM] += v.x;
        row[(e0 + 1) / DIM] += v.y; col[(e0 + 1) % DIM] += v.y;
        row[(e0 + 2) / DIM] += v.z; col[(e0 + 2) % DIM] += v.z;
        row[(e0 + 3) / DIM] += v.w; col[(e0 + 3) % DIM] += v.w;
    }

    // ---- Phase 3 (x4 probe): 55 lower-triangle pixels ----
    float acc[DIM][DIM];
    #pragma unroll
    for (int i = 0; i < DIM; ++i)
        #pragma unroll
        for (int j = 0; j < DIM; ++j) acc[i][j] = 0.f;

    #pragma unroll 1
    for (int rep = 0; rep < 4; ++rep) {
        float opaq = 0.0f;
        asm volatile("" : "+v"(opaq));   // opaque 0.0f: new value each rep
        // multiplicative re-zero: depends on previous rep's acc -> no DCE;
        // numerically exact 0 (acc is finite).
        #pragma unroll
        for (int i = 0; i < DIM; ++i)
            #pragma unroll
            for (int j = 0; j < DIM; ++j) acc[i][j] *= opaq;

        #pragma unroll
        for (int p = 0; p < DIM; ++p) {
            #pragma unroll
            for (int q = 0; q <= p; ++q) {
                // + opaq (== +0.0f) makes every downstream value depend on the
                // per-rep opaque -> no CSE across reps.
                const float e = row[p] + col[q] + opaq;
                const v2f e2 = (v2f){e, e};
                v2f s2[9];
                #pragma unroll
                for (int k = 0; k < 9; ++k) s2[k] = (v2f){0.f, 0.f};
                #pragma unroll
                for (int cp = 0; cp < 5; ++cp) {
                    const v2f g = vmax2(vfma2(W1p[cp], e2, B1p[cp]), (v2f){0.f, 0.f});
                    #pragma unroll
                    for (int k = 0; k < 9; ++k) s2[k] = vfma2(g, W2p[cp][k], s2[k]);
                }
                float s[9];
                #pragma unroll
                for (int k = 0; k < 9; ++k) s[k] = s2[k][0] + s2[k][1];
                #pragma unroll
                for (int a = 0; a < 3; ++a) {
                    const int i = p + 1 - a;
                    if (i < 0 || i >= DIM) continue;
                    #pragma unroll
                    for (int bb = 0; bb < 3; ++bb) {
                        const int j = q + 1 - bb;
                        if (j < 0 || j >= DIM) continue;
                        acc[i][j] += s[a * 3 + bb];
                    }
                }
            }
        }
    }

    // ---- m = relu(acc + b2); v[k] = row-sum + col-sum ----
    float vsum[DIM];
    #pragma unroll
    for (int k = 0; k < DIM; ++k) vsum[k] = 0.f;
    #pragma unroll
    for (int i = 0; i < DIM; ++i) {
        #pragma unroll
        for (int j = 0; j < DIM; ++j) {
            const float m = fmaxf(acc[i][j] + B2, 0.f);
            vsum[i] += m;
            vsum[j] += m;
        }
    }

    // ---- FC head ----
    float hid[4];
    #pragma unroll
    for (int t = 0; t < 4; ++t) {
        float a = fc1_b[t];
        #pragma unroll
        for (int k = 0; k < DIM; ++k) a = fmaf(vsum[k], fc1_w[t * DIM + k], a);
        hid[t] = fmaxf(a, 0.f);
    }
    float o0 = fc2_b[0], o1 = fc2_b[1];
    #pragma unroll
    for (int t = 0; t < 4; ++t) {
        o0 = fmaf(hid[t], fc2_w[t], o0);
        o1 = fmaf(hid[t], fc2_w[4 + t], o1);
    }
    reinterpret_cast<float2*>(out)[blk_elem0 + tid] = make_float2(o0, o1);
}

extern "C" void kernel_launch(void* const* d_in, const int* in_sizes, int n_in,
                              void* d_out, int out_size, void* d_ws, size_t ws_size,
                              hipStream_t stream) {
    const float* x     = (const float*)d_in[0];
    const float* w1    = (const float*)d_in[1];
    const float* b1    = (const float*)d_in[2];
    const float* w2    = (const float*)d_in[3];
    const float* b2    = (const float*)d_in[4];
    const float* fc1_w = (const float*)d_in[5];
    const float* fc1_b = (const float*)d_in[6];
    const float* fc2_w = (const float*)d_in[7];
    const float* fc2_b = (const float*)d_in[8];
    float* out = (float*)d_out;

    const int block = 256;
    const int grid = BATCH / block;
    net_kernel<<<grid, block, 0, stream>>>(x, w1, b1, w2, b2, fc1_w, fc1_b,
                                           fc2_w, fc2_b, out);
}

// Round 6
// 16.047 us; speedup vs baseline: 2.5370x; 2.5370x over previous
//
#include <hip/hip_runtime.h>

#define DIM 10
#define BATCH 65536

typedef _Float16 h2 __attribute__((ext_vector_type(2)));

#if defined(__has_builtin)
#  if __has_builtin(__builtin_amdgcn_fdot2)
#    define HAS_FDOT2 1
#  endif
#endif
#ifndef HAS_FDOT2
#  define HAS_FDOT2 0
#endif

// Conv core on the f16 pipe (2x f32 rate): g = pk_max_f16(pk_fma_f16(...)),
// 90 MACs/pixel as 45 v_dot2_f32_f16 with f32 accumulator chain.
// Staging: wave-private LDS quarters, NO __syncthreads (each wave only
// reads the region it staged; vmcnt(0) is a wave-level wait).
__launch_bounds__(256, 1)
__global__ void net_kernel(const float* __restrict__ x,
                           const float* __restrict__ w1,
                           const float* __restrict__ b1,
                           const float* __restrict__ w2,
                           const float* __restrict__ b2,
                           const float* __restrict__ fc1_w,
                           const float* __restrict__ fc1_b,
                           const float* __restrict__ fc2_w,
                           const float* __restrict__ fc2_b,
                           float* __restrict__ out) {
    __shared__ __align__(16) float xs[256 * DIM * DIM];

    const int tid  = threadIdx.x;
    const int wave = tid >> 6;
    const int lane = tid & 63;
    const size_t blk0 = (size_t)blockIdx.x * 256;

    // ---- Phase 1: wave-private coalesced staging (25 x 1 KiB per wave) ----
    const float* gbase = x + (blk0 + (size_t)wave * 64) * (DIM * DIM);
    float* lbase = xs + wave * 64 * (DIM * DIM);
    #pragma unroll
    for (int c = 0; c < 25; ++c) {
        __builtin_amdgcn_global_load_lds(
            (const __attribute__((address_space(1))) void*)(gbase + c * 256 + lane * 4),
            (__attribute__((address_space(3))) void*)(lbase + c * 256),
            16, 0, 0);
    }

    // ---- weights -> packed f16 (runs under the staging latency) ----
    h2 W1h[5], B1h[5], W2h[5][9];
    #pragma unroll
    for (int cp = 0; cp < 5; ++cp) {
        W1h[cp][0] = (_Float16)w1[2 * cp];     W1h[cp][1] = (_Float16)w1[2 * cp + 1];
        B1h[cp][0] = (_Float16)b1[2 * cp];     B1h[cp][1] = (_Float16)b1[2 * cp + 1];
        #pragma unroll
        for (int k = 0; k < 9; ++k) {
            W2h[cp][k][0] = (_Float16)w2[(2 * cp) * 9 + k];
            W2h[cp][k][1] = (_Float16)w2[(2 * cp + 1) * 9 + k];
        }
    }
    const float B2 = b2[0];

    // wave-level wait for our own 25 chunks; "memory" clobber orders the
    // following ds_reads after it.
    asm volatile("s_waitcnt vmcnt(0)" ::: "memory");

    // ---- Phase 2: per-thread row/col sums from own LDS row ----
    float row[DIM], col[DIM];
    #pragma unroll
    for (int i = 0; i < DIM; ++i) { row[i] = 0.f; col[i] = 0.f; }
    const float4* xb = reinterpret_cast<const float4*>(xs + tid * (DIM * DIM));
    #pragma unroll
    for (int t = 0; t < 25; ++t) {
        const float4 v = xb[t];
        const int e0 = t * 4;
        row[(e0 + 0) / DIM] += v.x; col[(e0 + 0) % DIM] += v.x;
        row[(e0 + 1) / DIM] += v.y; col[(e0 + 1) % DIM] += v.y;
        row[(e0 + 2) / DIM] += v.z; col[(e0 + 2) % DIM] += v.z;
        row[(e0 + 3) / DIM] += v.w; col[(e0 + 3) % DIM] += v.w;
    }

    // ---- Phase 3: 55 lower-triangle pixels, f16 dot2 core ----
    float acc[DIM][DIM];
    #pragma unroll
    for (int i = 0; i < DIM; ++i)
        #pragma unroll
        for (int j = 0; j < DIM; ++j) acc[i][j] = 0.f;

    const h2 zero_h2 = (h2){(_Float16)0, (_Float16)0};

    #pragma unroll
    for (int p = 0; p < DIM; ++p) {
        #pragma unroll
        for (int q = 0; q <= p; ++q) {
            const float e = row[p] + col[q];
            float s[9];
            #pragma unroll
            for (int k = 0; k < 9; ++k) s[k] = 0.f;
#if HAS_FDOT2
            const _Float16 eh = (_Float16)e;
            const h2 e2 = (h2){eh, eh};
            #pragma unroll
            for (int cp = 0; cp < 5; ++cp) {
                h2 g = __builtin_elementwise_fma(W1h[cp], e2, B1h[cp]);
                g = __builtin_elementwise_max(g, zero_h2);
                #pragma unroll
                for (int k = 0; k < 9; ++k)
                    s[k] = __builtin_amdgcn_fdot2(g, W2h[cp][k], s[k], false);
            }
#else
            #pragma unroll
            for (int cp = 0; cp < 5; ++cp) {
                const float g0 = fmaxf(fmaf((float)W1h[cp][0], e, (float)B1h[cp][0]), 0.f);
                const float g1 = fmaxf(fmaf((float)W1h[cp][1], e, (float)B1h[cp][1]), 0.f);
                #pragma unroll
                for (int k = 0; k < 9; ++k) {
                    s[k] = fmaf(g0, (float)W2h[cp][k][0], s[k]);
                    s[k] = fmaf(g1, (float)W2h[cp][k][1], s[k]);
                }
            }
#endif
            // scatter: source (p,q) feeds out (p+1-a, q+1-bb), tap k=a*3+bb
            #pragma unroll
            for (int a = 0; a < 3; ++a) {
                const int i = p + 1 - a;
                if (i < 0 || i >= DIM) continue;          // folds at compile time
                #pragma unroll
                for (int bb = 0; bb < 3; ++bb) {
                    const int j = q + 1 - bb;
                    if (j < 0 || j >= DIM) continue;
                    acc[i][j] += s[a * 3 + bb];
                }
            }
        }
    }

    // ---- m = relu(acc + b2); v[k] = row-sum + col-sum ----
    float vsum[DIM];
    #pragma unroll
    for (int k = 0; k < DIM; ++k) vsum[k] = 0.f;
    #pragma unroll
    for (int i = 0; i < DIM; ++i) {
        #pragma unroll
        for (int j = 0; j < DIM; ++j) {
            const float m = fmaxf(acc[i][j] + B2, 0.f);
            vsum[i] += m;
            vsum[j] += m;
        }
    }

    // ---- FC head (f32, uniform weight loads) ----
    float hid[4];
    #pragma unroll
    for (int t = 0; t < 4; ++t) {
        float a = fc1_b[t];
        #pragma unroll
        for (int k = 0; k < DIM; ++k) a = fmaf(vsum[k], fc1_w[t * DIM + k], a);
        hid[t] = fmaxf(a, 0.f);
    }
    float o0 = fc2_b[0], o1 = fc2_b[1];
    #pragma unroll
    for (int t = 0; t < 4; ++t) {
        o0 = fmaf(hid[t], fc2_w[t], o0);
        o1 = fmaf(hid[t], fc2_w[4 + t], o1);
    }
    reinterpret_cast<float2*>(out)[blk0 + tid] = make_float2(o0, o1);
}

extern "C" void kernel_launch(void* const* d_in, const int* in_sizes, int n_in,
                              void* d_out, int out_size, void* d_ws, size_t ws_size,
                              hipStream_t stream) {
    const float* x     = (const float*)d_in[0];
    const float* w1    = (const float*)d_in[1];
    const float* b1    = (const float*)d_in[2];
    const float* w2    = (const float*)d_in[3];
    const float* b2    = (const float*)d_in[4];
    const float* fc1_w = (const float*)d_in[5];
    const float* fc1_b = (const float*)d_in[6];
    const float* fc2_w = (const float*)d_in[7];
    const float* fc2_b = (const float*)d_in[8];
    float* out = (float*)d_out;

    const int block = 256;
    const int grid = BATCH / block;   // 256 blocks, 1 per CU
    net_kernel<<<grid, block, 0, stream>>>(x, w1, b1, w2, b2, fc1_w, fc1_b,
                                           fc2_w, fc2_b, out);
}